// Round 11
// baseline (280.675 us; speedup 1.0000x reference)
//
#include <hip/hip_runtime.h>
#include <hip/hip_bf16.h>
#include <stdint.h>

#define K_DIM 4096
#define N_DIM 4096
#define TOKENS 8192

#define BM 256
#define BN 256
#define BK 32
#define NT (K_DIM / BK)        // 128 k-tiles

// LDS ring of 3 slots; slot = { A[256r][64B row] (16 KB) | B[256c][64B row] (16 KB) }.
// Row = 4 chunks of 16B; phys chunk = logical ^ ((row>>1)&3)  (2-way max banking).
// Store side realizes the swizzle by pre-permuting the per-lane GLOBAL chunk
// (k4), keeping the gload_lds LDS dest linear (rule: both-sides-or-neither).
#define UNIT 16384
#define SLOT 32768
#define RING_BYTES (3 * SLOT)   // 96 KB -> 1 block/CU, but counted-vmcnt pipeline

typedef __attribute__((ext_vector_type(8))) short bf16x8;
typedef __attribute__((ext_vector_type(4))) float f32x4;

#define LDSV(p) ((__attribute__((address_space(3))) void*)(p))
#define GLBV(p) ((const __attribute__((address_space(1))) void*)(p))
#define MEMFENCE asm volatile("" ::: "memory")

__device__ inline unsigned short f2bf(float f) {
    union { float f; unsigned u; } v; v.f = f;
    unsigned r = v.u + 0x7FFF + ((v.u >> 16) & 1);   // RNE
    return (unsigned short)(r >> 16);
}

// ------- fused prepass: blocks [0,16384) convert x fp32->bf16;
//         blocks [16384,17408) GPTQ-dequant -> W^T bf16 [N][K] -------
#define CVT_BLOCKS 16384
__global__ __launch_bounds__(256) void prep_kernel(
    const float* __restrict__ x, unsigned short* __restrict__ xbf,
    const int* __restrict__ qweight, const int* __restrict__ qzeros,
    const float* __restrict__ scales, unsigned short* __restrict__ wt)
{
    const int b = blockIdx.x;
    if (b < CVT_BLOCKS) {
        size_t idx = ((size_t)b * 256 + threadIdx.x) * 8;
        const float4 v0 = *reinterpret_cast<const float4*>(&x[idx]);
        const float4 v1 = *reinterpret_cast<const float4*>(&x[idx + 4]);
        ushort4 h0, h1;
        h0.x = f2bf(v0.x); h0.y = f2bf(v0.y); h0.z = f2bf(v0.z); h0.w = f2bf(v0.w);
        h1.x = f2bf(v1.x); h1.y = f2bf(v1.y); h1.z = f2bf(v1.z); h1.w = f2bf(v1.w);
        *reinterpret_cast<ushort4*>(&xbf[idx]) = h0;
        *reinterpret_cast<ushort4*>(&xbf[idx + 4]) = h1;
    } else {
        const int idx = (b - CVT_BLOCKS) * 256 + threadIdx.x;
        const int kb = idx >> 12;            // 0..63  (block of 64 k)
        const int n  = idx & (N_DIM - 1);
        const int kr0 = kb * 8;
        const int g = kb >> 1;               // group: (kb*64)/128
        const float sc = scales[(size_t)g * N_DIM + n];
        const int zq = qzeros[(size_t)g * (N_DIM / 8) + (n >> 3)];
        const float zf = (float)(((zq >> ((n & 7) * 4)) & 0xF) + 1);

        unsigned short* dst = &wt[(size_t)n * K_DIM + kb * 64];
#pragma unroll
        for (int i = 0; i < 8; i++) {
            const int q = qweight[(size_t)(kr0 + i) * N_DIM + n];
            bf16x8 wv;
#pragma unroll
            for (int s = 0; s < 8; s++) {
                const float w = (float)((q >> (s * 4)) & 0xF) - zf;
                wv[s] = (short)f2bf(sc * w);
            }
            *reinterpret_cast<bf16x8*>(&dst[i * 8]) = wv;
        }
    }
}

// ----- main GEMM: 256x256, 8 waves, ring-3 counted-vmcnt pipeline, BK=32 -----
// Per tile t (cur=t%3, nxt=(t+1)%3, stg=(t+2)%3):
//   S1 stage tile t+2 -> stg (4 gloads)       [never waited until 1.5 tiles later]
//   S2 afB <- cur (4 ds_reads)
//   C1 16 MFMA (afA x b1, afA x b0) ; C2 8 MFMA (afB x b1)
//   vmcnt(4)  <- waits t+1's loads only; t+2's 4 stay in flight (T4 discipline)
//   barrier   <- sole barrier/tile; all reads of any slot precede the barrier
//                that precedes that slot's overwrite (checked r11 ledger)
//   S7a afA,b1 <- nxt (6 reads) ; C3 8 MFMA (afB x b0) ; S7b b0 <- nxt (2 reads)
__global__ __launch_bounds__(512, 2) void gemm_r3_kernel(
    const unsigned short* __restrict__ xbf, const unsigned short* __restrict__ wt,
    const float* __restrict__ bias, float* __restrict__ out)
{
    __shared__ __align__(16) char lds[RING_BYTES];   // 96 KB

    const int tid  = threadIdx.x;
    const int lane = tid & 63;
    const int wave = tid >> 6;
    const int wm = wave >> 2;        // 0..1 : 128-row M slice
    const int wn = wave & 3;         // 0..3 : 64-col N slice
    const int fr = lane & 15;
    const int fq = lane >> 4;

    const int m0 = blockIdx.x * BM;
    const int n0 = blockIdx.y * BN;

    // staging: wave covers 16 rows x 64B per gload; source chunk pre-permuted
    const int srow = wave * 16 + (lane >> 2);            // row within 128-row half
    const int k4   = (lane & 3) ^ ((lane >> 3) & 3);     // permuted 16B chunk

    // fragment read offset: logical chunk fq, phys = fq ^ ((fr>>1)&3)
    const int cx = ((fq ^ ((fr >> 1) & 3)) << 4);
    const int aoffs = wm * 8192 + fr * 64;               // + mi*1024, mi 0..7
    const int boffs = UNIT + wn * 4096 + fr * 64;        // + ni*1024, ni 0..3

    f32x4 acc[8][4];
#pragma unroll
    for (int i = 0; i < 8; i++)
#pragma unroll
        for (int j = 0; j < 4; j++) acc[i][j] = (f32x4){0.f, 0.f, 0.f, 0.f};

#define STAGE_A(slb, tt) do {                                                   \
    const int _k = (tt) * BK + k4 * 8;                                          \
    __builtin_amdgcn_global_load_lds(                                           \
        GLBV(xbf + (size_t)(m0 + srow) * K_DIM + _k),                           \
        LDSV(lds + (slb) + wave * 1024), 16, 0, 0);                             \
    __builtin_amdgcn_global_load_lds(                                           \
        GLBV(xbf + (size_t)(m0 + 128 + srow) * K_DIM + _k),                     \
        LDSV(lds + (slb) + 8192 + wave * 1024), 16, 0, 0); } while (0)

#define STAGE_B(slb, tt) do {                                                   \
    const int _k = (tt) * BK + k4 * 8;                                          \
    __builtin_amdgcn_global_load_lds(                                           \
        GLBV(wt + (size_t)(n0 + srow) * K_DIM + _k),                            \
        LDSV(lds + (slb) + UNIT + wave * 1024), 16, 0, 0);                      \
    __builtin_amdgcn_global_load_lds(                                           \
        GLBV(wt + (size_t)(n0 + 128 + srow) * K_DIM + _k),                      \
        LDSV(lds + (slb) + UNIT + 8192 + wave * 1024), 16, 0, 0); } while (0)

#define LD8(off) (*reinterpret_cast<const bf16x8*>(lds + (off)))

    // ---- prologue: stage tiles 0,1; wait tile 0 (tile 1's 4 stay in flight)
    STAGE_A(0, 0); STAGE_B(0, 0);
    STAGE_A(SLOT, 1); STAGE_B(SLOT, 1);
    asm volatile("s_waitcnt vmcnt(4)" ::: "memory");
    __builtin_amdgcn_s_barrier();

    bf16x8 afA[4], afB[4], b0[2], b1[2];
#pragma unroll
    for (int mi = 0; mi < 4; ++mi) afA[mi] = LD8(aoffs + mi * 1024 + cx);
#pragma unroll
    for (int ni = 0; ni < 2; ++ni) {
        b0[ni] = LD8(boffs + ni * 1024 + cx);
        b1[ni] = LD8(boffs + (ni + 2) * 1024 + cx);
    }

    int s0 = 0, s1 = SLOT, s2 = 2 * SLOT;   // byte bases of cur / nxt / stage slots

#pragma unroll 1
    for (int t = 0; t < NT; ++t) {
        const bool st2  = (t + 2) < NT;
        const bool more = (t + 1) < NT;

        // S1: stage tile t+2 into slot s2
        if (st2) { STAGE_A(s2, t + 2); STAGE_B(s2, t + 2); }

        // S2: afB <- m-rows 64..127 of cur
#pragma unroll
        for (int mi = 0; mi < 4; ++mi) afB[mi] = LD8(s0 + aoffs + (mi + 4) * 1024 + cx);
        __builtin_amdgcn_sched_barrier(0);

        // C1: afA x b1 (b1 long-drained), then afA x b0
        __builtin_amdgcn_s_setprio(1);
#pragma unroll
        for (int mi = 0; mi < 4; ++mi)
#pragma unroll
            for (int ni = 0; ni < 2; ++ni)
                acc[mi][ni + 2] = __builtin_amdgcn_mfma_f32_16x16x32_bf16(
                    afA[mi], b1[ni], acc[mi][ni + 2], 0, 0, 0);
#pragma unroll
        for (int mi = 0; mi < 4; ++mi)
#pragma unroll
            for (int ni = 0; ni < 2; ++ni)
                acc[mi][ni] = __builtin_amdgcn_mfma_f32_16x16x32_bf16(
                    afA[mi], b0[ni], acc[mi][ni], 0, 0, 0);
        __builtin_amdgcn_s_setprio(0);
        __builtin_amdgcn_sched_barrier(0);

        // C2: afB x b1 -> Q11 (b1 dies)
        __builtin_amdgcn_s_setprio(1);
#pragma unroll
        for (int mi = 0; mi < 4; ++mi)
#pragma unroll
            for (int ni = 0; ni < 2; ++ni)
                acc[mi + 4][ni + 2] = __builtin_amdgcn_mfma_f32_16x16x32_bf16(
                    afB[mi], b1[ni], acc[mi + 4][ni + 2], 0, 0, 0);
        __builtin_amdgcn_s_setprio(0);

        // counted wait: t+1's 4 loads must land; t+2's 4 may stay in flight
        if (st2) { asm volatile("s_waitcnt vmcnt(4)" ::: "memory"); }
        else     { asm volatile("s_waitcnt vmcnt(0)" ::: "memory"); }
        MEMFENCE; __builtin_amdgcn_s_barrier(); MEMFENCE;

        // S7a: afA, b1 <- nxt (t+1), overlapping C3
        if (more) {
#pragma unroll
            for (int mi = 0; mi < 4; ++mi) afA[mi] = LD8(s1 + aoffs + mi * 1024 + cx);
#pragma unroll
            for (int ni = 0; ni < 2; ++ni) b1[ni] = LD8(s1 + boffs + (ni + 2) * 1024 + cx);
        }
        __builtin_amdgcn_sched_barrier(0);

        // C3: afB x b0 -> Q10 (b0 dies)
        __builtin_amdgcn_s_setprio(1);
#pragma unroll
        for (int mi = 0; mi < 4; ++mi)
#pragma unroll
            for (int ni = 0; ni < 2; ++ni)
                acc[mi + 4][ni] = __builtin_amdgcn_mfma_f32_16x16x32_bf16(
                    afB[mi], b0[ni], acc[mi + 4][ni], 0, 0, 0);
        __builtin_amdgcn_s_setprio(0);

        // S7b: b0 <- nxt (first use is late in next C1)
        if (more) {
#pragma unroll
            for (int ni = 0; ni < 2; ++ni) b0[ni] = LD8(s1 + boffs + ni * 1024 + cx);
        }

        // rotate ring
        const int tmp = s0; s0 = s1; s1 = s2; s2 = tmp;
    }

    // ---- epilogue: C/D layout col=lane&15, row=(lane>>4)*4+j
#pragma unroll
    for (int ni = 0; ni < 4; ++ni) {
        const int col = n0 + wn * 64 + ni * 16 + fr;
        const float bv = bias[col];
#pragma unroll
        for (int mi = 0; mi < 8; ++mi) {
            const int row = m0 + wm * 128 + mi * 16 + fq * 4;
#pragma unroll
            for (int j = 0; j < 4; ++j)
                out[(size_t)(row + j) * N_DIM + col] = acc[mi][ni][j] + bv;
        }
    }
#undef STAGE_A
#undef STAGE_B
#undef LD8
}

// ---------------- fallback (round-1 fused kernel, ws too small) ----------------
#define FBM 128
#define FBK 64
#define LDS_K (FBK + 8)
__global__ __launch_bounds__(256, 2) void q4gemm_kernel(
    const float* __restrict__ x, const int* __restrict__ qweight,
    const int* __restrict__ qzeros, const float* __restrict__ scales,
    const float* __restrict__ bias, float* __restrict__ out)
{
    __shared__ unsigned short As[FBM][LDS_K];
    __shared__ unsigned short Bs[FBM][LDS_K];
    const int tid = threadIdx.x, lane = tid & 63, wave = tid >> 6;
    const int wr = wave >> 1, wc = wave & 1;
    const int m0 = blockIdx.x * FBM, nn0 = blockIdx.y * FBM;
    const int fr = lane & 15, fq = lane >> 4, kfrag = fq << 3;
    f32x4 acc[4][4];
#pragma unroll
    for (int i = 0; i < 4; i++)
#pragma unroll
        for (int j = 0; j < 4; j++) acc[i][j] = (f32x4){0.f, 0.f, 0.f, 0.f};
    for (int k0 = 0; k0 < K_DIM; k0 += FBK) {
        const int g = k0 >> 7;
#pragma unroll
        for (int i = 0; i < 8; i++) {
            int idx = tid + i * 256, row = idx >> 4, c4 = (idx & 15) << 2;
            const float4 v = *reinterpret_cast<const float4*>(
                &x[(size_t)(m0 + row) * K_DIM + k0 + c4]);
            ushort4 h; h.x = f2bf(v.x); h.y = f2bf(v.y); h.z = f2bf(v.z); h.w = f2bf(v.w);
            *reinterpret_cast<ushort4*>(&As[row][c4]) = h;
        }
#pragma unroll
        for (int i = 0; i < 4; i++) {
            int idx = tid + i * 256, krl = idx >> 7, nl = idx & 127, n = nn0 + nl;
            int q = qweight[(size_t)(k0 / 8 + krl) * N_DIM + n];
            float sc = scales[(size_t)g * N_DIM + n];
            int zq = qzeros[(size_t)g * (N_DIM / 8) + (n >> 3)];
            int z = ((zq >> ((n & 7) * 4)) & 0xF) + 1;
            bf16x8 wv;
#pragma unroll
            for (int s = 0; s < 8; s++)
                wv[s] = (short)f2bf(sc * (float)(((q >> (s * 4)) & 0xF) - z));
            *reinterpret_cast<bf16x8*>(&Bs[nl][krl * 8]) = wv;
        }
        __syncthreads();
        bf16x8 a_frag[2][4], b_frag[2][4];
#pragma unroll
        for (int ks = 0; ks < 2; ks++) {
            const int kb = ks * 32 + kfrag;
#pragma unroll
            for (int mi = 0; mi < 4; mi++)
                a_frag[ks][mi] = *reinterpret_cast<const bf16x8*>(&As[wr * 64 + mi * 16 + fr][kb]);
#pragma unroll
            for (int ni = 0; ni < 4; ni++)
                b_frag[ks][ni] = *reinterpret_cast<const bf16x8*>(&Bs[wc * 64 + ni * 16 + fr][kb]);
        }
#pragma unroll
        for (int ks = 0; ks < 2; ks++)
#pragma unroll
            for (int mi = 0; mi < 4; mi++)
#pragma unroll
                for (int ni = 0; ni < 4; ni++)
                    acc[mi][ni] = __builtin_amdgcn_mfma_f32_16x16x32_bf16(
                        a_frag[ks][mi], b_frag[ks][ni], acc[mi][ni], 0, 0, 0);
        __syncthreads();
    }
#pragma unroll
    for (int ni = 0; ni < 4; ni++) {
        const int col = nn0 + wc * 64 + ni * 16 + fr;
        const float bv = bias[col];
#pragma unroll
        for (int mi = 0; mi < 4; mi++)
#pragma unroll
            for (int j = 0; j < 4; j++) {
                const int row = m0 + wr * 64 + mi * 16 + fq * 4 + j;
                out[(size_t)row * N_DIM + col] = acc[mi][ni][j] + bv;
            }
    }
}

extern "C" void kernel_launch(void* const* d_in, const int* in_sizes, int n_in,
                              void* d_out, int out_size, void* d_ws, size_t ws_size,
                              hipStream_t stream) {
    const float* x       = (const float*)d_in[0];
    const int*   qweight = (const int*)d_in[1];
    const int*   qzeros  = (const int*)d_in[2];
    const float* scales  = (const float*)d_in[3];
    const float* bias    = (const float*)d_in[5];
    float*       out     = (float*)d_out;

    const size_t xbf_bytes = (size_t)TOKENS * K_DIM * 2;   // 64 MB
    const size_t wt_bytes  = (size_t)N_DIM * K_DIM * 2;    // 32 MB

    if (ws_size >= xbf_bytes + wt_bytes) {
        unsigned short* xbf = (unsigned short*)d_ws;
        unsigned short* wt  = (unsigned short*)((char*)d_ws + xbf_bytes);

        prep_kernel<<<CVT_BLOCKS + (N_DIM * (K_DIM / 64)) / 256, 256, 0, stream>>>(
            x, xbf, qweight, qzeros, scales, wt);
        dim3 grid(TOKENS / BM, N_DIM / BN);
        gemm_r3_kernel<<<grid, dim3(512), 0, stream>>>(xbf, wt, bias, out);
    } else {
        q4gemm_kernel<<<dim3(TOKENS / FBM, N_DIM / FBM), dim3(256), 0, stream>>>(
            x, qweight, qzeros, scales, bias, out);
    }
}